// Round 1
// 700.542 us; speedup vs baseline: 1.1488x; 1.1488x over previous
//
#include <hip/hip_runtime.h>
#include <stdint.h>

// AttentionPool, fused single-pass design.
// Inputs (f32 except blk_ptr i32): h_blk [N,128], W [128,128], b [128],
// context [128], blk_ptr [B+1].  Out (f32): h_file [B,128] ++ alpha [N].
//
// K0 (zero): h_file and D (workspace) zeroed (atomic accumulation targets).
// K1 (dense, fused): per 16-row tile: e[i] = exp(tanh(h_i W^T + b)·ctx) via
//    bf16 MFMA (scores bounded, no seg-max needed; exp clamped at 87).
//    While the tile is LDS-resident, accumulate per-segment numerator
//    sum(e_i*h_i) (2 dims/lane) and denominator sum(e_i) in registers,
//    flushing with f32 atomics only at segment boundaries. h_blk is read
//    from HBM exactly ONCE. Waves own contiguous tile chunks so flushes
//    ~= one per segment per wave (~1.7M atomics total, ~7MB L2 RMW).
// K2 (finalize): h_file *= 1/D; alpha = e/D in place. (~18 MB traffic.)

typedef __attribute__((ext_vector_type(8))) short short8;
typedef __attribute__((ext_vector_type(4))) float f32x4;

#define DIM 128
#define WPAD 136    // 128 + 8 bf16 pad -> 272B row stride in LDS

struct __align__(16) SMemA {
  unsigned short W[128 * WPAD];      // 34816 B bf16, padded row-major
  unsigned short h[4][16 * WPAD];    // 17408 B per-wave 16-row bf16 tile
  float bias[DIM];                   //   512 B
  float ctx[DIM];                    //   512 B
  float e[4][16];                    //   256 B per-wave e values
};                                   // 53504 B -> 3 blocks/CU

__device__ inline unsigned short f2b(float f) {
  union { float f; uint32_t i; } v; v.f = f;
  uint32_t r = v.i + 0x7FFFu + ((v.i >> 16) & 1u);   // RNE
  return (unsigned short)(r >> 16);
}
__device__ inline float tanh_fast(float x) {
  float e2 = __expf(2.0f * x);
  return 1.0f - 2.0f * __builtin_amdgcn_rcpf(e2 + 1.0f);
}
__device__ inline void atomic_add_f32(float* p, float v) {
  __hip_atomic_fetch_add(p, v, __ATOMIC_RELAXED, __HIP_MEMORY_SCOPE_AGENT);
}

// ---------------- K0: zero accumulation targets ----------------
__global__ void zero_kernel(float* __restrict__ hf, float* __restrict__ Dg,
                            int n_hf, int n_d) {
  int i = (blockIdx.x * 256 + threadIdx.x) * 4;
  if (i < n_hf) *(float4*)&hf[i] = make_float4(0.f, 0.f, 0.f, 0.f);
  if (i < n_d) {
    if (i + 3 < n_d) *(float4*)&Dg[i] = make_float4(0.f, 0.f, 0.f, 0.f);
    else for (int k = i; k < n_d; ++k) Dg[k] = 0.f;
  }
}

// ---------------- K1: dense scores + fused segment pooling ----------------
__global__ __launch_bounds__(256, 3) void scores_kernel(
    const float* __restrict__ h_blk,
    const float* __restrict__ Wg,
    const float* __restrict__ bg,
    const float* __restrict__ cg,
    const int* __restrict__ bp,
    float* __restrict__ e_out,
    float* __restrict__ h_file,
    float* __restrict__ Dg,
    int N, int B)
{
  __shared__ SMemA sm;
  const int tid  = threadIdx.x;
  const int wave = tid >> 6;
  const int lane = tid & 63;

  // stage W (f32 -> bf16) + bias/ctx
  {
    const float4* Wg4 = (const float4*)Wg;          // 4096 chunks of 4 f32
    for (int rep = 0; rep < 16; ++rep) {
      int c = rep * 256 + tid;
      int row  = c >> 5;
      int col4 = (c & 31) * 4;
      float4 v = Wg4[c];
      ushort4 o;
      o.x = f2b(v.x); o.y = f2b(v.y); o.z = f2b(v.z); o.w = f2b(v.w);
      *(ushort4*)&sm.W[row * WPAD + col4] = o;
    }
    if (tid < DIM) { sm.bias[tid] = bg[tid]; sm.ctx[tid] = cg[tid]; }
  }
  __syncthreads();

  const int quad = lane >> 4;
  const int mrow = lane & 15;
  const int ntiles = (N + 15) >> 4;
  const int gw = blockIdx.x * 4 + wave;
  const int nw = gridDim.x * 4;
  // contiguous tile chunk per wave: register accumulation spans whole
  // segments (avg ~6 tiles) -> flush atomics ~once per segment per wave
  const int cpw = (ntiles + nw - 1) / nw;
  const int t0 = gw * cpw;
  const int t1 = min(t0 + cpw, ntiles);
  if (t0 >= t1) return;                 // no barriers past this point

  const float4* hg4 = (const float4*)h_blk;
  unsigned short* ht = sm.h[wave];
  float* ebuf = sm.e[wave];

  // segment pointer: largest cur with bp[cur] <= first row (uniform)
  int cur, nxt;
  {
    int r0r = t0 << 4;
    int lo = 0, hi = B;                 // bp[0]=0 <= r0r < N = bp[B]
    while (hi - lo > 1) {
      int mid = (lo + hi) >> 1;
      if (bp[mid] <= r0r) lo = mid; else hi = mid;
    }
    cur = lo; nxt = bp[lo + 1];
  }

  float num0 = 0.f, num1 = 0.f, dsum = 0.f;   // per-lane dims j0, j0+1
  const int j0 = lane * 2;

  auto flush = [&]() {
    atomic_add_f32(&h_file[(size_t)cur * DIM + j0],     num0);
    atomic_add_f32(&h_file[(size_t)cur * DIM + j0 + 1], num1);
    if (lane == 0) atomic_add_f32(&Dg[cur], dsum);
    num0 = num1 = dsum = 0.f;
  };

  // preload tile t0 into registers
  float4 v[8];
  {
    int tb = t0 << 4; int rows = min(16, N - tb);
#pragma unroll
    for (int rep = 0; rep < 8; ++rep) {
      int c = rep * 64 + lane; int row = c >> 5;
      v[rep] = (row < rows) ? hg4[(size_t)(tb + row) * 32 + (c & 31)]
                            : make_float4(0.f, 0.f, 0.f, 0.f);
    }
  }

  for (int t = t0; t < t1; ++t) {
    const int tb = t << 4;
    const int rows = min(16, N - tb);

    // stage registers -> bf16 LDS (wave-private, no barrier)
#pragma unroll
    for (int rep = 0; rep < 8; ++rep) {
      int c = rep * 64 + lane;
      int row  = c >> 5;
      int col4 = (c & 31) * 4;
      ushort4 o;
      o.x = f2b(v[rep].x); o.y = f2b(v[rep].y);
      o.z = f2b(v[rep].z); o.w = f2b(v[rep].w);
      *(ushort4*)&ht[row * WPAD + col4] = o;
    }

    // prefetch next tile: HBM latency hides under MFMA/tanh below
    if (t + 1 < t1) {
      int tb2 = (t + 1) << 4; int rows2 = min(16, N - tb2);
#pragma unroll
      for (int rep = 0; rep < 8; ++rep) {
        int c = rep * 64 + lane; int row = c >> 5;
        v[rep] = (row < rows2) ? hg4[(size_t)(tb2 + row) * 32 + (c & 31)]
                               : make_float4(0.f, 0.f, 0.f, 0.f);
      }
    }

    const unsigned short* ar = &ht[mrow * WPAD + quad * 8];
    short8 a0 = *(const short8*)&ar[0];
    short8 a1 = *(const short8*)&ar[32];
    short8 a2 = *(const short8*)&ar[64];
    short8 a3 = *(const short8*)&ar[96];

    float part0 = 0.f, part1 = 0.f, part2 = 0.f, part3 = 0.f;
    for (int nt = 0; nt < 8; ++nt) {
      const unsigned short* wr = &sm.W[(nt * 16 + mrow) * WPAD + quad * 8];
      short8 b0 = *(const short8*)&wr[0];
      short8 b1 = *(const short8*)&wr[32];
      short8 b2 = *(const short8*)&wr[64];
      short8 b3 = *(const short8*)&wr[96];
      f32x4 c = {0.f, 0.f, 0.f, 0.f};
      c = __builtin_amdgcn_mfma_f32_16x16x32_bf16(a0, b0, c, 0, 0, 0);
      c = __builtin_amdgcn_mfma_f32_16x16x32_bf16(a1, b1, c, 0, 0, 0);
      c = __builtin_amdgcn_mfma_f32_16x16x32_bf16(a2, b2, c, 0, 0, 0);
      c = __builtin_amdgcn_mfma_f32_16x16x32_bf16(a3, b3, c, 0, 0, 0);
      // C/D: col = lane&15 (output col nt*16+mrow), row = quad*4+reg
      float bj = sm.bias[nt * 16 + mrow];
      float cj = sm.ctx[nt * 16 + mrow];
      part0 += tanh_fast(c.x + bj) * cj;
      part1 += tanh_fast(c.y + bj) * cj;
      part2 += tanh_fast(c.z + bj) * cj;
      part3 += tanh_fast(c.w + bj) * cj;
    }
    for (int m = 1; m <= 8; m <<= 1) {
      part0 += __shfl_xor(part0, m);
      part1 += __shfl_xor(part1, m);
      part2 += __shfl_xor(part2, m);
      part3 += __shfl_xor(part3, m);
    }
    float e0 = __expf(fminf(part0, 87.f)), e1 = __expf(fminf(part1, 87.f));
    float e2 = __expf(fminf(part2, 87.f)), e3 = __expf(fminf(part3, 87.f));
    if (mrow == 0) {
      int rb = quad * 4;
      if (rows == 16) {
        *(float4*)&e_out[tb + rb] = make_float4(e0, e1, e2, e3);
      } else {
        if (rb + 0 < rows) e_out[tb + rb + 0] = e0;
        if (rb + 1 < rows) e_out[tb + rb + 1] = e1;
        if (rb + 2 < rows) e_out[tb + rb + 2] = e2;
        if (rb + 3 < rows) e_out[tb + rb + 3] = e3;
      }
      *(float4*)&ebuf[rb] = make_float4(e0, e1, e2, e3);  // wave-private
    }

    // fused pooling: accumulate e_i * h_i for this tile (h from bf16 LDS,
    // rel err 2^-9 -> <~0.002 abs on h_file; e from LDS broadcast).
    // seg advance is wave-uniform; flush only at segment boundaries.
    for (int i = 0; i < rows; ++i) {
      int r = tb + i;
      if (r >= nxt) {
        flush();
        do { ++cur; nxt = bp[cur + 1]; } while (nxt <= r);
      }
      float ei = ebuf[i];
      uint32_t u = *(const uint32_t*)&ht[i * WPAD + j0];
      num0 += ei * __uint_as_float(u << 16);
      num1 += ei * __uint_as_float(u & 0xFFFF0000u);
      dsum += ei;
    }
  }
  flush();
}

// ---------------- K2: finalize (scale by 1/D) ----------------
__global__ __launch_bounds__(128) void finalize_kernel(
    const int* __restrict__ bp,
    const float* __restrict__ Dg,
    float* __restrict__ h_file,
    float* __restrict__ e_alpha)      // in: e, out: alpha (in place)
{
  const int seg = blockIdx.x;
  const int tid = threadIdx.x;
  const float D = Dg[seg];
  const float rD = (D > 0.f) ? (1.0f / D) : 0.f;
  h_file[(size_t)seg * DIM + tid] *= rD;
  const int r0 = bp[seg];
  const int r1 = bp[seg + 1];
  for (int i = r0 + tid; i < r1; i += 128) {
    e_alpha[i] *= rD;
  }
}

extern "C" void kernel_launch(void* const* d_in, const int* in_sizes, int n_in,
                              void* d_out, int out_size, void* d_ws, size_t ws_size,
                              hipStream_t stream) {
  const float* h_blk = (const float*)d_in[0];
  const float* Wg    = (const float*)d_in[1];
  const float* bg    = (const float*)d_in[2];
  const float* cg    = (const float*)d_in[3];
  const int*   bp    = (const int*)d_in[4];
  const int N = in_sizes[0] / DIM;
  const int B = in_sizes[4] - 1;

  float* out    = (float*)d_out;
  float* h_file = out;                      // [B,128]
  float* alpha  = out + (size_t)B * DIM;    // [N]; also holds e between K1,K2
  float* Dg     = (float*)d_ws;             // [B] denominators

  const int n_hf = B * DIM;
  const int zero_blocks = (n_hf / 4 + 255) / 256;
  zero_kernel<<<dim3(zero_blocks), dim3(256), 0, stream>>>(h_file, Dg, n_hf, B);
  scores_kernel<<<dim3(768), dim3(256), 0, stream>>>(h_blk, Wg, bg, cg, bp,
                                                     alpha, h_file, Dg, N, B);
  finalize_kernel<<<dim3(B), dim3(128), 0, stream>>>(bp, Dg, h_file, alpha);
}

// Round 4
// 699.438 us; speedup vs baseline: 1.1506x; 1.0016x over previous
//
#include <hip/hip_runtime.h>
#include <stdint.h>

// AttentionPool, fused single-pass design (v3, resubmitted — round 3 was an
// infra failure, kernel never ran).
// v1 (passed, 700us) + row-parallel pooling sourced from the bf16 LDS tile.
// Control flow, prefetch, and segment-advance are byte-identical to v1;
// ONLY the per-tile pooling body changed (serial 16-iter scalar chain ->
// 8 unrolled ds_read_b64 + 32 FMAs for interior tiles; v1's serial loop,
// parity-masked, for the ~16% of tiles containing a segment boundary).
//
// K0 (zero): h_file and D (workspace) zeroed (atomic accumulation targets).
// K1 (dense, fused): per 16-row tile: e[i] = exp(tanh(h_i W^T + b)·ctx) via
//    bf16 MFMA (scores bounded, no seg-max needed; exp clamped at 87).
//    Fused pooling accumulates per-segment sum(e_i*h_i) (4 dims/lane,
//    row-parity split across lane halves) and sum(e_i) in registers,
//    flushing with f32 atomics only at segment boundaries. h_blk is read
//    from HBM exactly ONCE.
// K2 (finalize): h_file *= 1/D; alpha = e/D in place. (~18 MB traffic.)

typedef __attribute__((ext_vector_type(8))) short short8;
typedef __attribute__((ext_vector_type(4))) float f32x4;

#define DIM 128
#define WPAD 136    // 128 + 8 bf16 pad -> 272B row stride in LDS

struct __align__(16) SMemA {
  unsigned short W[128 * WPAD];      // 34816 B bf16, padded row-major
  unsigned short h[4][16 * WPAD];    // 17408 B per-wave 16-row bf16 tile
  float bias[DIM];                   //   512 B
  float ctx[DIM];                    //   512 B
  float e[4][16];                    //   256 B per-wave e values
};                                   // 53504 B -> 3 blocks/CU (LDS-limited)

__device__ inline unsigned short f2b(float f) {
  union { float f; uint32_t i; } v; v.f = f;
  uint32_t r = v.i + 0x7FFFu + ((v.i >> 16) & 1u);   // RNE
  return (unsigned short)(r >> 16);
}
__device__ inline float tanh_fast(float x) {
  float e2 = __expf(2.0f * x);
  return 1.0f - 2.0f * __builtin_amdgcn_rcpf(e2 + 1.0f);
}
__device__ inline void atomic_add_f32(float* p, float v) {
  __hip_atomic_fetch_add(p, v, __ATOMIC_RELAXED, __HIP_MEMORY_SCOPE_AGENT);
}

// ---------------- K0: zero accumulation targets ----------------
__global__ void zero_kernel(float* __restrict__ hf, float* __restrict__ Dg,
                            int n_hf, int n_d) {
  int i = (blockIdx.x * 256 + threadIdx.x) * 4;
  if (i < n_hf) *(float4*)&hf[i] = make_float4(0.f, 0.f, 0.f, 0.f);
  if (i < n_d) {
    if (i + 3 < n_d) *(float4*)&Dg[i] = make_float4(0.f, 0.f, 0.f, 0.f);
    else for (int k = i; k < n_d; ++k) Dg[k] = 0.f;
  }
}

// ---------------- K1: dense scores + fused segment pooling ----------------
__global__ __launch_bounds__(256, 3) void scores_kernel(
    const float* __restrict__ h_blk,
    const float* __restrict__ Wg,
    const float* __restrict__ bg,
    const float* __restrict__ cg,
    const int* __restrict__ bp,
    float* __restrict__ e_out,
    float* __restrict__ h_file,
    float* __restrict__ Dg,
    int N, int B)
{
  __shared__ SMemA sm;
  const int tid  = threadIdx.x;
  const int wave = tid >> 6;
  const int lane = tid & 63;

  // stage W (f32 -> bf16) + bias/ctx
  {
    const float4* Wg4 = (const float4*)Wg;          // 4096 chunks of 4 f32
    for (int rep = 0; rep < 16; ++rep) {
      int c = rep * 256 + tid;
      int row  = c >> 5;
      int col4 = (c & 31) * 4;
      float4 v = Wg4[c];
      ushort4 o;
      o.x = f2b(v.x); o.y = f2b(v.y); o.z = f2b(v.z); o.w = f2b(v.w);
      *(ushort4*)&sm.W[row * WPAD + col4] = o;
    }
    if (tid < DIM) { sm.bias[tid] = bg[tid]; sm.ctx[tid] = cg[tid]; }
  }
  __syncthreads();

  const int quad = lane >> 4;
  const int mrow = lane & 15;
  const int hl   = lane >> 5;           // row parity this lane accumulates
  const int dq   = lane & 31;           // dim group: dims 4*dq..4*dq+3
  const int ntiles = (N + 15) >> 4;
  const int gw = blockIdx.x * 4 + wave;
  const int nw = gridDim.x * 4;
  // contiguous tile chunk per wave: register accumulation spans whole
  // segments (avg ~6 tiles) -> flush atomics ~once per segment per wave
  const int cpw = (ntiles + nw - 1) / nw;
  const int t0 = gw * cpw;
  const int t1 = min(t0 + cpw, ntiles);
  if (t0 >= t1) return;                 // no barriers past this point

  const float4* hg4 = (const float4*)h_blk;
  unsigned short* ht = sm.h[wave];
  float* ebuf = sm.e[wave];

  // segment pointer: largest cur with bp[cur] <= first row (wave-uniform)
  int cur, nxt;
  {
    int r0r = t0 << 4;
    int lo = 0, hi = B;                 // bp[0]=0 <= r0r < N = bp[B]
    while (hi - lo > 1) {
      int mid = (lo + hi) >> 1;
      if (bp[mid] <= r0r) lo = mid; else hi = mid;
    }
    cur = lo; nxt = bp[lo + 1];
  }

  // per-lane accumulators: dims 4*dq..+3, rows of parity hl
  float4 acc = make_float4(0.f, 0.f, 0.f, 0.f);
  float dsum = 0.f;

  auto flushv = [&]() {
    float4 s = acc;
    s.x += __shfl_xor(s.x, 32);
    s.y += __shfl_xor(s.y, 32);
    s.z += __shfl_xor(s.z, 32);
    s.w += __shfl_xor(s.w, 32);
    float dd = dsum + __shfl_xor(dsum, 32);
    if (lane < 32) {
      float* p = &h_file[(size_t)cur * DIM + lane * 4];
      atomic_add_f32(p + 0, s.x);
      atomic_add_f32(p + 1, s.y);
      atomic_add_f32(p + 2, s.z);
      atomic_add_f32(p + 3, s.w);
    }
    if (lane == 0) atomic_add_f32(&Dg[cur], dd);
    acc = make_float4(0.f, 0.f, 0.f, 0.f);
    dsum = 0.f;
  };

  // preload tile t0 into registers
  float4 v[8];
  {
    int tb = t0 << 4; int rows = min(16, N - tb);
#pragma unroll
    for (int rep = 0; rep < 8; ++rep) {
      int c = rep * 64 + lane; int row = c >> 5;
      v[rep] = (row < rows) ? hg4[(size_t)(tb + row) * 32 + (c & 31)]
                            : make_float4(0.f, 0.f, 0.f, 0.f);
    }
  }

  for (int t = t0; t < t1; ++t) {
    const int tb = t << 4;
    const int rows = min(16, N - tb);

    // stage registers -> bf16 LDS (wave-private, no barrier)
#pragma unroll
    for (int rep = 0; rep < 8; ++rep) {
      int c = rep * 64 + lane;
      int row  = c >> 5;
      int col4 = (c & 31) * 4;
      ushort4 o;
      o.x = f2b(v[rep].x); o.y = f2b(v[rep].y);
      o.z = f2b(v[rep].z); o.w = f2b(v[rep].w);
      *(ushort4*)&ht[row * WPAD + col4] = o;
    }

    // prefetch next tile: HBM latency hides under MFMA/tanh below
    if (t + 1 < t1) {
      int tb2 = (t + 1) << 4; int rows2 = min(16, N - tb2);
#pragma unroll
      for (int rep = 0; rep < 8; ++rep) {
        int c = rep * 64 + lane; int row = c >> 5;
        v[rep] = (row < rows2) ? hg4[(size_t)(tb2 + row) * 32 + (c & 31)]
                               : make_float4(0.f, 0.f, 0.f, 0.f);
      }
    }

    const unsigned short* ar = &ht[mrow * WPAD + quad * 8];
    short8 a0 = *(const short8*)&ar[0];
    short8 a1 = *(const short8*)&ar[32];
    short8 a2 = *(const short8*)&ar[64];
    short8 a3 = *(const short8*)&ar[96];

    float part0 = 0.f, part1 = 0.f, part2 = 0.f, part3 = 0.f;
    for (int nt = 0; nt < 8; ++nt) {
      const unsigned short* wr = &sm.W[(nt * 16 + mrow) * WPAD + quad * 8];
      short8 b0 = *(const short8*)&wr[0];
      short8 b1 = *(const short8*)&wr[32];
      short8 b2 = *(const short8*)&wr[64];
      short8 b3 = *(const short8*)&wr[96];
      f32x4 c = {0.f, 0.f, 0.f, 0.f};
      c = __builtin_amdgcn_mfma_f32_16x16x32_bf16(a0, b0, c, 0, 0, 0);
      c = __builtin_amdgcn_mfma_f32_16x16x32_bf16(a1, b1, c, 0, 0, 0);
      c = __builtin_amdgcn_mfma_f32_16x16x32_bf16(a2, b2, c, 0, 0, 0);
      c = __builtin_amdgcn_mfma_f32_16x16x32_bf16(a3, b3, c, 0, 0, 0);
      // C/D: col = lane&15 (output col nt*16+mrow), row = quad*4+reg
      float bj = sm.bias[nt * 16 + mrow];
      float cj = sm.ctx[nt * 16 + mrow];
      part0 += tanh_fast(c.x + bj) * cj;
      part1 += tanh_fast(c.y + bj) * cj;
      part2 += tanh_fast(c.z + bj) * cj;
      part3 += tanh_fast(c.w + bj) * cj;
    }
    for (int m = 1; m <= 8; m <<= 1) {
      part0 += __shfl_xor(part0, m);
      part1 += __shfl_xor(part1, m);
      part2 += __shfl_xor(part2, m);
      part3 += __shfl_xor(part3, m);
    }
    float e0 = __expf(fminf(part0, 87.f)), e1 = __expf(fminf(part1, 87.f));
    float e2 = __expf(fminf(part2, 87.f)), e3 = __expf(fminf(part3, 87.f));
    if (mrow == 0) {
      int rb = quad * 4;
      if (rows == 16) {
        *(float4*)&e_out[tb + rb] = make_float4(e0, e1, e2, e3);
      } else {
        if (rb + 0 < rows) e_out[tb + rb + 0] = e0;
        if (rb + 1 < rows) e_out[tb + rb + 1] = e1;
        if (rb + 2 < rows) e_out[tb + rb + 2] = e2;
        if (rb + 3 < rows) e_out[tb + rb + 3] = e3;
      }
      *(float4*)&ebuf[rb] = make_float4(e0, e1, e2, e3);  // wave-private
    }

    // fused pooling from bf16 LDS tile (rel err 2^-9, same as v1).
    if (rows == 16 && nxt - tb >= 16) {
      // interior tile: row-parallel, fully unrolled, no serial chain.
      // lane reads rows 2*rep+hl at dims 4*dq..+3 (ds_read_b64, 2-way=free)
#pragma unroll
      for (int rep = 0; rep < 8; ++rep) {
        int row = rep * 2 + hl;
        float ei = ebuf[row];
        uint2 u = *(const uint2*)&ht[row * WPAD + dq * 4];
        acc.x += ei * __uint_as_float(u.x << 16);
        acc.y += ei * __uint_as_float(u.x & 0xFFFF0000u);
        acc.z += ei * __uint_as_float(u.y << 16);
        acc.w += ei * __uint_as_float(u.y & 0xFFFF0000u);
        dsum += ei;
      }
    } else {
      // boundary tile (~16%): v1's proven serial advance, parity-masked
      for (int i = 0; i < rows; ++i) {
        int r = tb + i;
        if (r >= nxt) {
          flushv();
          do { ++cur; nxt = bp[cur + 1]; } while (nxt <= r);
        }
        if ((i & 1) == hl) {
          float ei = ebuf[i];
          uint2 u = *(const uint2*)&ht[i * WPAD + dq * 4];
          acc.x += ei * __uint_as_float(u.x << 16);
          acc.y += ei * __uint_as_float(u.x & 0xFFFF0000u);
          acc.z += ei * __uint_as_float(u.y << 16);
          acc.w += ei * __uint_as_float(u.y & 0xFFFF0000u);
          dsum += ei;
        }
      }
    }
  }
  flushv();
}

// ---------------- K2: finalize (scale by 1/D) ----------------
__global__ __launch_bounds__(128) void finalize_kernel(
    const int* __restrict__ bp,
    const float* __restrict__ Dg,
    float* __restrict__ h_file,
    float* __restrict__ e_alpha)      // in: e, out: alpha (in place)
{
  const int seg = blockIdx.x;
  const int tid = threadIdx.x;
  const float D = Dg[seg];
  const float rD = (D > 0.f) ? (1.0f / D) : 0.f;
  h_file[(size_t)seg * DIM + tid] *= rD;
  const int r0 = bp[seg];
  const int r1 = bp[seg + 1];
  for (int i = r0 + tid; i < r1; i += 128) {
    e_alpha[i] *= rD;
  }
}

extern "C" void kernel_launch(void* const* d_in, const int* in_sizes, int n_in,
                              void* d_out, int out_size, void* d_ws, size_t ws_size,
                              hipStream_t stream) {
  const float* h_blk = (const float*)d_in[0];
  const float* Wg    = (const float*)d_in[1];
  const float* bg    = (const float*)d_in[2];
  const float* cg    = (const float*)d_in[3];
  const int*   bp    = (const int*)d_in[4];
  const int N = in_sizes[0] / DIM;
  const int B = in_sizes[4] - 1;

  float* out    = (float*)d_out;
  float* h_file = out;                      // [B,128]
  float* alpha  = out + (size_t)B * DIM;    // [N]; also holds e between K1,K2
  float* Dg     = (float*)d_ws;             // [B] denominators

  const int n_hf = B * DIM;
  const int zero_blocks = (n_hf / 4 + 255) / 256;
  zero_kernel<<<dim3(zero_blocks), dim3(256), 0, stream>>>(h_file, Dg, n_hf, B);
  scores_kernel<<<dim3(768), dim3(256), 0, stream>>>(h_blk, Wg, bg, cg, bp,
                                                     alpha, h_file, Dg, N, B);
  finalize_kernel<<<dim3(B), dim3(128), 0, stream>>>(bp, Dg, h_file, alpha);
}